// Round 5
// baseline (257.473 us; speedup 1.0000x reference)
//
#include <hip/hip_runtime.h>
#include <hip/hip_bf16.h>
#include <stdint.h>

// Problem constants
#define BT   768
#define NN   512
#define DIN  64
#define HID  128
#define EMB  16
#define SLOPE 0.01f

typedef __attribute__((ext_vector_type(8))) short bf16x8;   // 8 bf16 (4 VGPRs)
typedef __attribute__((ext_vector_type(4))) float f32x4;    // MFMA C/D frag
typedef __attribute__((ext_vector_type(4))) short short4v;

__device__ __forceinline__ short f2bf(float f) {            // fp32 -> bf16 RNE
    uint32_t u = __float_as_uint(f);
    u += 0x7fff + ((u >> 16) & 1);
    return (short)(u >> 16);
}
__device__ __forceinline__ float bf2f(short s) {
    return __uint_as_float(((uint32_t)(unsigned short)s) << 16);
}

// ---------------- workspace layout (bytes) ----------------
// Spatial weights pre-folded with W1: wcomb[n][o][k] = (W1 @ Wspa[n])^T
// h2 stored [n][R][o] (n-major): k_spatial writes contiguous per-n streams.
static const size_t OFF_WCOMB = 0;          // [512][128 o][64 k] bf16 = 8.4 MB
static const size_t OFF_WTEM  = 8388608;    // [768][128][128] bf16 = 25.2 MB
static const size_t OFF_BSPA  = 33554432;   // [512][128] fp32
static const size_t OFF_BTEM  = 33816576;   // [768][128] fp32
static const size_t OFF_Q     = 34209792;   // q[d][o] = b1 @ pool_spa[d], [16][128] fp32
static const size_t OFF_PTT   = 34217984;   // pool_tem^T bf16 [d][o][i]
static const size_t OFF_PTS2  = 34742272;   // P^T bf16 [d][o=128][k=64]; P[d]=W1@pool_spa[d]
static const size_t OFF_H2    = 35004416;   // bf16 [n][R][o]

// ---------------------------------------------------------------------------
// k_prep (unchanged)
// ---------------------------------------------------------------------------
__global__ __launch_bounds__(256)
void k_prep(const float* __restrict__ pool_spa, const float* __restrict__ pool_tem,
            const float* __restrict__ W1, const float* __restrict__ b1,
            const float* __restrict__ bp_spa, const float* __restrict__ bp_tem,
            const float* __restrict__ node_eb, const float* __restrict__ time_eb,
            short* __restrict__ ptt, short* __restrict__ pts2,
            float* __restrict__ qtab, float* __restrict__ bspa,
            float* __restrict__ btem)
{
    const int b = blockIdx.x, t = threadIdx.x;
    __shared__ short smem[26112];            // 52.2 KB max (P^T branch)

    if (b < 64) {                            // ---- pool_tem transpose ----
        const int d = b >> 2, o0 = (b & 3) * 32;
        short* s = smem;                     // [32][136]
        #pragma unroll
        for (int c = 0; c < 16; ++c) {
            int e = c * 256 + t;
            int i = e >> 5, oo = e & 31;
            s[oo * 136 + i] = f2bf(pool_tem[(d * HID + i) * HID + o0 + oo]);
        }
        __syncthreads();
        #pragma unroll
        for (int c = 0; c < 8; ++c) {
            int e = c * 256 + t;
            int oo = e >> 6, ii = (e & 63) * 2;
            uint32_t lo = (unsigned short)s[oo * 136 + ii];
            uint32_t hi = (unsigned short)s[oo * 136 + ii + 1];
            ((uint32_t*)ptt)[((d * HID + o0 + oo) * HID + ii) >> 1] = lo | (hi << 16);
        }
        return;
    }
    if (b < 224) {                           // ---- fused genb ----
        int q = (b - 64) * 256 + t;          // float4 index
        const float *bp, *emb; float* outp;
        if (q < NN * 32) { bp = bp_spa; emb = node_eb; outp = bspa; }
        else { q -= NN * 32; bp = bp_tem; emb = time_eb; outp = btem; }
        const int n = q >> 5, oq = q & 31;
        float4 a = make_float4(0.f, 0.f, 0.f, 0.f);
        #pragma unroll
        for (int d = 0; d < EMB; ++d) {
            float e = emb[n * EMB + d];
            float4 bv = ((const float4*)bp)[d * 32 + oq];
            a.x += e * bv.x; a.y += e * bv.y; a.z += e * bv.z; a.w += e * bv.w;
        }
        ((float4*)outp)[q] = a;
        return;
    }
    if (b < 226) {                           // ---- q table ----
        const int dbase = (b - 224) * 8;
        if (t < 128) {
            float a[8] = {};
            for (int i = 0; i < HID; ++i) {
                float bv = b1[i];
                #pragma unroll
                for (int dd = 0; dd < 8; ++dd)
                    a[dd] += bv * pool_spa[((dbase + dd) * HID + i) * HID + t];
            }
            #pragma unroll
            for (int dd = 0; dd < 8; ++dd) qtab[(dbase + dd) * HID + t] = a[dd];
        }
        return;
    }
    // ---- P^T[d] = (pool_spa[d]^T @ W1^T) : out [o=128][k=64], contraction i=128
    {
        const int d = b - 226;
        const int wave = t >> 6, lane = t & 63, quad = lane >> 4, l15 = lane & 15;
        const int m0 = wave * 32;
        short* sPT  = smem;                  // [128][136] pool^T bf16 [o][i]
        short* sW1b = smem + 128 * 136;      // [64][136]  W1 bf16 [k][i]
        #pragma unroll
        for (int c = 0; c < 64; ++c) {
            int idx = c * 256 + t;
            int i = idx >> 7, o = idx & 127;
            sPT[o * 136 + i] = f2bf(pool_spa[(d * HID + i) * HID + o]);
        }
        #pragma unroll
        for (int c = 0; c < 32; ++c) {
            int idx = c * 256 + t;           // W1 is [k=64][i=128] row-major
            sW1b[(idx >> 7) * 136 + (idx & 127)] = f2bf(W1[idx]);
        }
        __syncthreads();
        f32x4 acc[2][4] = {};
        #pragma unroll
        for (int kc = 0; kc < 4; ++kc) {
            bf16x8 a0 = *(const bf16x8*)(sPT + (m0 + l15) * 136 + kc * 32 + quad * 8);
            bf16x8 a1 = *(const bf16x8*)(sPT + (m0 + 16 + l15) * 136 + kc * 32 + quad * 8);
            #pragma unroll
            for (int tc = 0; tc < 4; ++tc) {
                bf16x8 bb = *(const bf16x8*)(sW1b + (tc * 16 + l15) * 136 + kc * 32 + quad * 8);
                acc[0][tc] = __builtin_amdgcn_mfma_f32_16x16x32_bf16(a0, bb, acc[0][tc], 0, 0, 0);
                acc[1][tc] = __builtin_amdgcn_mfma_f32_16x16x32_bf16(a1, bb, acc[1][tc], 0, 0, 0);
            }
        }
        __syncthreads();
        short* sO = smem;                    // reuse: [128][72]
        #pragma unroll
        for (int tr = 0; tr < 2; ++tr)
            #pragma unroll
            for (int tc = 0; tc < 4; ++tc)
                #pragma unroll
                for (int r = 0; r < 4; ++r)
                    sO[(m0 + tr * 16 + quad * 4 + r) * 72 + tc * 16 + l15] = f2bf(acc[tr][tc][r]);
        __syncthreads();
        #pragma unroll
        for (int c = 0; c < 4; ++c) {
            int idx = c * 256 + t;
            int row = idx >> 3, ko = (idx & 7) * 8;
            *(bf16x8*)(pts2 + (size_t)d * 8192 + row * 64 + ko) =
                *(const bf16x8*)(sO + row * 72 + ko);
        }
    }
}

// ---------------------------------------------------------------------------
// k_genw (unchanged)
// ---------------------------------------------------------------------------
__global__ __launch_bounds__(256)
void k_genw(const short* __restrict__ pts2, const short* __restrict__ ptt,
            const float* __restrict__ node_eb, const float* __restrict__ time_eb,
            short* __restrict__ wcomb, short* __restrict__ wtem)
{
    const int t = threadIdx.x, b = blockIdx.x;
    int nb, cq, stride;
    const short* pool; const float* emb; short* outp;
    if (b < 64) {
        nb = b >> 3; cq = (b & 7) * 256 + t; stride = 2048;
        pool = pts2; emb = node_eb; outp = wcomb;
    } else {
        int bb = b - 64;
        nb = bb >> 4; cq = (bb & 15) * 256 + t; stride = 4096;
        pool = ptt; emb = time_eb; outp = wtem;
    }
    __shared__ float sEmb[64 * EMB];
    #pragma unroll
    for (int c = 0; c < 4; ++c) {
        int idx = c * 256 + t;
        sEmb[idx] = emb[nb * 64 * EMB + idx];
    }
    __syncthreads();
    float4 p[EMB];
    #pragma unroll
    for (int d = 0; d < EMB; ++d) {
        short4v v = ((const short4v*)pool)[d * stride + cq];
        p[d] = make_float4(bf2f(v.x), bf2f(v.y), bf2f(v.z), bf2f(v.w));
    }
    for (int nn = 0; nn < 64; ++nn) {
        float4 a = make_float4(0.f, 0.f, 0.f, 0.f);
        #pragma unroll
        for (int d = 0; d < EMB; ++d) {
            float e = sEmb[nn * EMB + d];
            a.x += e * p[d].x; a.y += e * p[d].y;
            a.z += e * p[d].z; a.w += e * p[d].w;
        }
        short4v o;
        o.x = f2bf(a.x); o.y = f2bf(a.y); o.z = f2bf(a.z); o.w = f2bf(a.w);
        ((short4v*)outp)[(size_t)(nb * 64 + nn) * stride + cq] = o;
    }
}

// ---------------------------------------------------------------------------
// k_spatial v5: 4 n per block (one per wave), weights REGISTER-resident.
// eb is read in 1 KB contiguous spans (4 adjacent n x 64 k fp32 per row) to
// fix DRAM row-buffer efficiency (was 256 B @ pow2 128 KB stride -> ~2.5 TB/s
// ceiling). Per-wave-private sOut slice -> 1 barrier/chunk.
// Grid (128 n-groups, 4 R-spans of 192) = 512 blocks = exactly 2/CU.
// LDS 71,936 B -> 2 blocks/CU.
// ---------------------------------------------------------------------------
#define NSL 2320                             // sEb n-slice stride in shorts (padded)
__global__ __launch_bounds__(256)
void k_spatial(const float* __restrict__ eb, const short* __restrict__ wcomb,
               const float* __restrict__ bspa, const float* __restrict__ qtab,
               const float* __restrict__ node_eb, short* __restrict__ h2)
{
    const int n0 = blockIdx.x * 4;           // 4 n per block, one per wave
    const int Rbase = blockIdx.y * 192;      // 6 chunks of 32 rows
    const int t = threadIdx.x;
    const int wave = t >> 6, lane = t & 63, quad = lane >> 4, l15 = lane & 15;
    const int n = n0 + wave;

    __shared__ short sEb[2][4 * NSL];        // 2 x 18,560 B  (bf16 [4n][32r][72])
    __shared__ short sOut[4][32 * 136];      // 34,816 B, one slice per wave

    // ---- issue chunk-0 eb loads: per row one contiguous 1 KB span ----
    float4 ev[8];
    #pragma unroll
    for (int c = 0; c < 8; ++c) {
        int idx = c * 256 + t;
        int r = idx >> 6, f4 = idx & 63;
        ev[c] = *(const float4*)(eb + (size_t)(Rbase + r) * (NN * DIN) + n0 * DIN + f4 * 4);
    }
    // ---- B fragments: wcomb[n] -> registers (16 x bf16x8 = 64 VGPR) ----
    bf16x8 Breg[8][2];
    #pragma unroll
    for (int tc = 0; tc < 8; ++tc)
        #pragma unroll
        for (int kc = 0; kc < 2; ++kc)
            Breg[tc][kc] = *(const bf16x8*)(wcomb + (size_t)n * 8192
                                            + (tc * 16 + l15) * 64 + kc * 32 + quad * 8);
    // ---- combined bias: bspa[n] + node_eb[n] @ qtab ----
    float bsr[8];
    #pragma unroll
    for (int tc = 0; tc < 8; ++tc) {
        int col = tc * 16 + l15;
        float a = bspa[n * HID + col];
        #pragma unroll
        for (int d = 0; d < EMB; ++d)
            a += node_eb[n * EMB + d] * qtab[d * HID + col];
        bsr[tc] = a;
    }
    // ---- stage chunk 0 ----
    #pragma unroll
    for (int c = 0; c < 8; ++c) {
        int idx = c * 256 + t;
        int r = idx >> 6, nsl = (idx & 63) >> 4, k4 = (idx & 15) * 4;
        short4v s;
        s.x = f2bf(ev[c].x); s.y = f2bf(ev[c].y);
        s.z = f2bf(ev[c].z); s.w = f2bf(ev[c].w);
        *(short4v*)(&sEb[0][nsl * NSL + r * 72 + k4]) = s;
    }
    __syncthreads();

    short* h2w = h2 + (size_t)n * (BT * HID) + (size_t)Rbase * HID;
    short* so  = &sOut[wave][0];

    int cur = 0;
    for (int ch = 0; ch < 6; ++ch) {
        // issue next chunk's loads (drain under MFMA + epilogue)
        if (ch < 5) {
            #pragma unroll
            for (int c = 0; c < 8; ++c) {
                int idx = c * 256 + t;
                int r = (ch + 1) * 32 + (idx >> 6), f4 = idx & 63;
                ev[c] = *(const float4*)(eb + (size_t)(Rbase + r) * (NN * DIN) + n0 * DIN + f4 * 4);
            }
        }
        // GEMM: [32r x 64k] @ Breg (per-wave n), 32 MFMA
        const short* se = &sEb[cur][wave * NSL];
        f32x4 acc[2][8] = {};
        #pragma unroll
        for (int kc = 0; kc < 2; ++kc) {
            bf16x8 a0 = *(const bf16x8*)(se + l15 * 72 + kc * 32 + quad * 8);
            bf16x8 a1 = *(const bf16x8*)(se + (16 + l15) * 72 + kc * 32 + quad * 8);
            #pragma unroll
            for (int tc = 0; tc < 8; ++tc) {
                acc[0][tc] = __builtin_amdgcn_mfma_f32_16x16x32_bf16(a0, Breg[tc][kc], acc[0][tc], 0, 0, 0);
                acc[1][tc] = __builtin_amdgcn_mfma_f32_16x16x32_bf16(a1, Breg[tc][kc], acc[1][tc], 0, 0, 0);
            }
        }
        // epilogue: bias + leaky -> per-wave sOut slice (no cross-wave hazard)
        #pragma unroll
        for (int tr = 0; tr < 2; ++tr)
            #pragma unroll
            for (int tc = 0; tc < 8; ++tc) {
                int col = tc * 16 + l15;
                #pragma unroll
                for (int r = 0; r < 4; ++r) {
                    float v = acc[tr][tc][r] + bsr[tc];
                    v = (v >= 0.f) ? v : SLOPE * v;
                    so[(tr * 16 + quad * 4 + r) * 136 + col] = f2bf(v);
                }
            }
        // stage next chunk into the other buffer (vmcnt wait lands here)
        if (ch < 5) {
            #pragma unroll
            for (int c = 0; c < 8; ++c) {
                int idx = c * 256 + t;
                int r = idx >> 6, nsl = (idx & 63) >> 4, k4 = (idx & 15) * 4;
                short4v s;
                s.x = f2bf(ev[c].x); s.y = f2bf(ev[c].y);
                s.z = f2bf(ev[c].z); s.w = f2bf(ev[c].w);
                *(short4v*)(&sEb[cur ^ 1][nsl * NSL + r * 72 + k4]) = s;
            }
            __syncthreads();             // sEb[nxt] staged; cur reads all done
        }
        // contiguous 8 KB h2 store per wave (own n stream)
        #pragma unroll
        for (int c = 0; c < 8; ++c) {
            int idx = c * 64 + lane;
            int row = idx >> 4, colg = (idx & 15) * 8;
            *(bf16x8*)(h2w + (size_t)(ch * 32 + row) * HID + colg) =
                *(const bf16x8*)(so + row * 136 + colg);
        }
        cur ^= 1;
    }
}

// ---------------------------------------------------------------------------
// k_temporal (unchanged): out[R][n][:] = leaky(h2[n][R]@Wtem[R]+btem[R]) @ W3 + b3
// ---------------------------------------------------------------------------
__global__ __launch_bounds__(256)
void k_temporal(const short* __restrict__ h2, const short* __restrict__ wtem,
                const float* __restrict__ btem, const float* __restrict__ W3,
                const float* __restrict__ b3, float* __restrict__ out)
{
    const int R = blockIdx.x, nbase = blockIdx.y * 256;
    const int t = threadIdx.x;
    const int wave = t >> 6, lane = t & 63, quad = lane >> 4, l15 = lane & 15;
    const int m0 = wave * 16;

    __shared__ short sWt[128 * 136];
    __shared__ short sH2[64 * 136];

    const short* hb = h2 + (size_t)R * HID;           // + n*BT*HID walks n

    bf16x8 wv[8];
    {
        const bf16x8* src = (const bf16x8*)(wtem + (size_t)R * 16384);
        #pragma unroll
        for (int c = 0; c < 8; ++c) wv[c] = src[c * 256 + t];
    }
    bf16x8 hreg[4];
    #pragma unroll
    for (int c = 0; c < 4; ++c) {
        int idx = c * 256 + t;
        hreg[c] = *(const bf16x8*)(hb + (size_t)(nbase + (idx >> 4)) * (BT * HID) + (idx & 15) * 8);
    }
    float btr[8], w3r0[8], w3r1[8];
    #pragma unroll
    for (int tc = 0; tc < 8; ++tc) {
        int o = tc * 16 + l15;
        btr[tc] = btem[R * HID + o];
        w3r0[tc] = W3[2 * o]; w3r1[tc] = W3[2 * o + 1];
    }
    const float b30 = b3[0], b31 = b3[1];

    #pragma unroll
    for (int c = 0; c < 8; ++c) {
        int idx = c * 256 + t;
        *(bf16x8*)(sWt + (idx >> 4) * 136 + (idx & 15) * 8) = wv[c];
    }
    #pragma unroll
    for (int c = 0; c < 4; ++c) {
        int idx = c * 256 + t;
        *(bf16x8*)(sH2 + (idx >> 4) * 136 + (idx & 15) * 8) = hreg[c];
    }
    __syncthreads();

    for (int nt = 0; nt < 4; ++nt) {
        if (nt < 3) {
            #pragma unroll
            for (int c = 0; c < 4; ++c) {
                int idx = c * 256 + t;
                hreg[c] = *(const bf16x8*)(hb + (size_t)(nbase + (nt + 1) * 64 + (idx >> 4)) * (BT * HID) + (idx & 15) * 8);
            }
        }
        f32x4 acc[8] = {};
        #pragma unroll
        for (int kc = 0; kc < 4; ++kc) {
            bf16x8 a = *(const bf16x8*)(sH2 + (m0 + l15) * 136 + kc * 32 + quad * 8);
            #pragma unroll
            for (int tc = 0; tc < 8; ++tc) {
                bf16x8 b = *(const bf16x8*)(sWt + (tc * 16 + l15) * 136 + kc * 32 + quad * 8);
                acc[tc] = __builtin_amdgcn_mfma_f32_16x16x32_bf16(a, b, acc[tc], 0, 0, 0);
            }
        }
        float pl[4][2] = {};
        #pragma unroll
        for (int tc = 0; tc < 8; ++tc) {
            #pragma unroll
            for (int r = 0; r < 4; ++r) {
                float v = acc[tc][r] + btr[tc];
                v = (v >= 0.f) ? v : SLOPE * v;
                pl[r][0] += v * w3r0[tc];
                pl[r][1] += v * w3r1[tc];
            }
        }
        #pragma unroll
        for (int m = 1; m <= 8; m <<= 1)
            #pragma unroll
            for (int r = 0; r < 4; ++r) {
                pl[r][0] += __shfl_xor(pl[r][0], m);
                pl[r][1] += __shfl_xor(pl[r][1], m);
            }
        if (l15 == 0) {
            #pragma unroll
            for (int r = 0; r < 4; ++r) {
                int nrow = nbase + nt * 64 + m0 + quad * 4 + r;
                *(float2*)(out + ((size_t)R * NN + nrow) * 2) =
                    make_float2(pl[r][0] + b30, pl[r][1] + b31);
            }
        }
        __syncthreads();
        if (nt < 3) {
            #pragma unroll
            for (int c = 0; c < 4; ++c) {
                int idx = c * 256 + t;
                *(bf16x8*)(sH2 + (idx >> 4) * 136 + (idx & 15) * 8) = hreg[c];
            }
            __syncthreads();
        }
    }
}

extern "C" void kernel_launch(void* const* d_in, const int* in_sizes, int n_in,
                              void* d_out, int out_size, void* d_ws, size_t ws_size,
                              hipStream_t stream) {
    const float* eb        = (const float*)d_in[0];
    const float* time_eb   = (const float*)d_in[1];
    const float* node_eb   = (const float*)d_in[2];
    const float* W1        = (const float*)d_in[3];
    const float* b1        = (const float*)d_in[4];
    const float* W3        = (const float*)d_in[5];
    const float* b3        = (const float*)d_in[6];
    const float* pool_spa  = (const float*)d_in[7];
    const float* bpool_spa = (const float*)d_in[8];
    const float* pool_tem  = (const float*)d_in[9];
    const float* bpool_tem = (const float*)d_in[10];
    float* out = (float*)d_out;

    char* ws = (char*)d_ws;
    short* wcomb = (short*)(ws + OFF_WCOMB);
    short* wtem  = (short*)(ws + OFF_WTEM);
    float* bspa  = (float*)(ws + OFF_BSPA);
    float* btem  = (float*)(ws + OFF_BTEM);
    float* qtab  = (float*)(ws + OFF_Q);
    short* ptt   = (short*)(ws + OFF_PTT);
    short* pts2  = (short*)(ws + OFF_PTS2);
    short* h2    = (short*)(ws + OFF_H2);

    k_prep<<<242, 256, 0, stream>>>(pool_spa, pool_tem, W1, b1, bpool_spa, bpool_tem,
                                    node_eb, time_eb, ptt, pts2, qtab, bspa, btem);
    k_genw<<<256, 256, 0, stream>>>(pts2, ptt, node_eb, time_eb, wcomb, wtem);
    k_spatial<<<dim3(128, 4), 256, 0, stream>>>(eb, wcomb, bspa, qtab, node_eb, h2);
    k_temporal<<<dim3(BT, 2), 256, 0, stream>>>(h2, wtem, btem, W3, b3, out);
}

// Round 6
// 243.076 us; speedup vs baseline: 1.0592x; 1.0592x over previous
//
#include <hip/hip_runtime.h>
#include <hip/hip_bf16.h>
#include <stdint.h>

// Problem constants
#define BT   768
#define NN   512
#define DIN  64
#define HID  128
#define EMB  16
#define SLOPE 0.01f

typedef __attribute__((ext_vector_type(8))) short bf16x8;   // 8 bf16 (4 VGPRs)
typedef __attribute__((ext_vector_type(4))) float f32x4;    // MFMA C/D frag
typedef __attribute__((ext_vector_type(4))) short short4v;

__device__ __forceinline__ short f2bf(float f) {            // fp32 -> bf16 RNE
    uint32_t u = __float_as_uint(f);
    u += 0x7fff + ((u >> 16) & 1);
    return (short)(u >> 16);
}
__device__ __forceinline__ float bf2f(short s) {
    return __uint_as_float(((uint32_t)(unsigned short)s) << 16);
}

// ---------------- workspace layout (bytes) ----------------
// Hypernetwork weights are NEVER materialized: consumers combine the tiny
// (L2-resident) pool tensors inline. Only pools + h2 live in the workspace.
static const size_t OFF_PTT  = 0;           // pool_tem^T bf16 [d][o=128][i=128] = 512 KB
static const size_t OFF_PTS2 = 524288;      // P^T bf16 [d][o=128][k=64]; P[d]=W1@pool_spa[d]
static const size_t OFF_QB   = 786432;      // qb[d][o] = bp_spa[d][o] + b1@pool_spa[d], fp32 [16][128]
static const size_t OFF_H2   = 1048576;     // bf16 [n][R][o] = 100.7 MB

// ---------------------------------------------------------------------------
// k_prep (82 blocks):
//   b 0..63  : transpose pool_tem -> ptt bf16 [d][o][i]
//   b 64..65 : qb[d][o] = bp_spa[d][o] + sum_i b1[i]*pool_spa[d][i][o]
//   b 66..81 : pts2: P^T[d][o][k] = sum_i pool_spa[d][i][o]*W1[k][i]  (MFMA)
// ---------------------------------------------------------------------------
__global__ __launch_bounds__(256)
void k_prep(const float* __restrict__ pool_spa, const float* __restrict__ pool_tem,
            const float* __restrict__ W1, const float* __restrict__ b1,
            const float* __restrict__ bp_spa,
            short* __restrict__ ptt, short* __restrict__ pts2,
            float* __restrict__ qb)
{
    const int b = blockIdx.x, t = threadIdx.x;
    __shared__ short smem[26112];            // 52.2 KB max (pts2 branch)

    if (b < 64) {                            // ---- pool_tem transpose ----
        const int d = b >> 2, o0 = (b & 3) * 32;
        short* s = smem;                     // [32][136]
        #pragma unroll
        for (int c = 0; c < 16; ++c) {
            int e = c * 256 + t;
            int i = e >> 5, oo = e & 31;
            s[oo * 136 + i] = f2bf(pool_tem[(d * HID + i) * HID + o0 + oo]);
        }
        __syncthreads();
        #pragma unroll
        for (int c = 0; c < 8; ++c) {
            int e = c * 256 + t;
            int oo = e >> 6, ii = (e & 63) * 2;
            uint32_t lo = (unsigned short)s[oo * 136 + ii];
            uint32_t hi = (unsigned short)s[oo * 136 + ii + 1];
            ((uint32_t*)ptt)[((d * HID + o0 + oo) * HID + ii) >> 1] = lo | (hi << 16);
        }
        return;
    }
    if (b < 66) {                            // ---- qb table ----
        const int dbase = (b - 64) * 8;
        if (t < 128) {
            float a[8];
            #pragma unroll
            for (int dd = 0; dd < 8; ++dd) a[dd] = bp_spa[(dbase + dd) * HID + t];
            for (int i = 0; i < HID; ++i) {
                float bv = b1[i];
                #pragma unroll
                for (int dd = 0; dd < 8; ++dd)
                    a[dd] += bv * pool_spa[((dbase + dd) * HID + i) * HID + t];
            }
            #pragma unroll
            for (int dd = 0; dd < 8; ++dd) qb[(dbase + dd) * HID + t] = a[dd];
        }
        return;
    }
    // ---- pts2: P^T[d] = (pool_spa[d]^T @ W1^T), out [o=128][k=64], contraction i=128
    {
        const int d = b - 66;
        const int wave = t >> 6, lane = t & 63, quad = lane >> 4, l15 = lane & 15;
        const int m0 = wave * 32;
        short* sPT  = smem;                  // [128][136] pool^T bf16 [o][i]
        short* sW1b = smem + 128 * 136;      // [64][136]  W1 bf16 [k][i]
        #pragma unroll
        for (int c = 0; c < 64; ++c) {
            int idx = c * 256 + t;
            int i = idx >> 7, o = idx & 127;
            sPT[o * 136 + i] = f2bf(pool_spa[(d * HID + i) * HID + o]);
        }
        #pragma unroll
        for (int c = 0; c < 32; ++c) {
            int idx = c * 256 + t;           // W1 is [k=64][i=128] row-major
            sW1b[(idx >> 7) * 136 + (idx & 127)] = f2bf(W1[idx]);
        }
        __syncthreads();
        f32x4 acc[2][4] = {};
        #pragma unroll
        for (int kc = 0; kc < 4; ++kc) {
            bf16x8 a0 = *(const bf16x8*)(sPT + (m0 + l15) * 136 + kc * 32 + quad * 8);
            bf16x8 a1 = *(const bf16x8*)(sPT + (m0 + 16 + l15) * 136 + kc * 32 + quad * 8);
            #pragma unroll
            for (int tc = 0; tc < 4; ++tc) {
                bf16x8 bb = *(const bf16x8*)(sW1b + (tc * 16 + l15) * 136 + kc * 32 + quad * 8);
                acc[0][tc] = __builtin_amdgcn_mfma_f32_16x16x32_bf16(a0, bb, acc[0][tc], 0, 0, 0);
                acc[1][tc] = __builtin_amdgcn_mfma_f32_16x16x32_bf16(a1, bb, acc[1][tc], 0, 0, 0);
            }
        }
        __syncthreads();
        short* sO = smem;                    // reuse: [128][72]
        #pragma unroll
        for (int tr = 0; tr < 2; ++tr)
            #pragma unroll
            for (int tc = 0; tc < 4; ++tc)
                #pragma unroll
                for (int r = 0; r < 4; ++r)
                    sO[(m0 + tr * 16 + quad * 4 + r) * 72 + tc * 16 + l15] = f2bf(acc[tr][tc][r]);
        __syncthreads();
        #pragma unroll
        for (int c = 0; c < 4; ++c) {
            int idx = c * 256 + t;
            int row = idx >> 3, ko = (idx & 7) * 8;
            *(bf16x8*)(pts2 + (size_t)d * 8192 + row * 64 + ko) =
                *(const bf16x8*)(sO + row * 72 + ko);
        }
    }
}

// ---------------------------------------------------------------------------
// k_spatial v6: v4 persistent-per-n structure (best measured, 62 us) with
// wcomb generated INLINE from pts2 (L2-hot 256 KB) at block entry -- the
// 8.4 MB wcomb tensor never exists. Bias from qb table (16 FMA/col).
// LDS 71,680 B -> 2 blocks/CU (grid 512 = exactly 2/CU).
// ---------------------------------------------------------------------------
__global__ __launch_bounds__(256)
void k_spatial(const float* __restrict__ eb, const short* __restrict__ pts2,
               const float* __restrict__ qb, const float* __restrict__ node_eb,
               short* __restrict__ h2)
{
    const int n = blockIdx.x;
    const int t = threadIdx.x;
    const int wave = t >> 6, lane = t & 63, quad = lane >> 4, l15 = lane & 15;
    const int m0 = (wave >> 1) * 32, n0 = (wave & 1) * 64;

    __shared__ short sW[128 * 72];       // wcomb[n] as [o][k]   18,432 B
    __shared__ short sEb[2][64 * 72];    // eb chunk, dbuf       18,432 B
    __shared__ short sOut[2][64 * 136];  // output staging, dbuf 34,816 B

    const float* ebn = eb + (size_t)n * DIN;          // + r*NN*DIN walks rows
    short* h2n = h2 + (size_t)n * (BT * HID);         // [n][R][o]: contiguous

    // ---- issue eb chunk-0 loads first (HBM latency hides under wcomb gen) ----
    float4 ev[4];
    #pragma unroll
    for (int c = 0; c < 4; ++c) {
        int idx = c * 256 + t;
        int r = idx >> 4, kq = (idx & 15) * 4;
        ev[c] = *(const float4*)(ebn + (size_t)r * (NN * DIN) + kq);
    }
    // ---- node embedding (uniform across block) ----
    float ne[EMB];
    #pragma unroll
    for (int d = 0; d < EMB; ++d) ne[d] = node_eb[n * EMB + d];
    // ---- combined bias: bsr = sum_d ne[d] * qb[d][col] ----
    float bsr[4];
    #pragma unroll
    for (int tc = 0; tc < 4; ++tc) {
        int col = n0 + tc * 16 + l15;
        float a = 0.f;
        #pragma unroll
        for (int d = 0; d < EMB; ++d) a += ne[d] * qb[d * HID + col];
        bsr[tc] = a;
    }
    // ---- inline wcomb: sW[o][k] = sum_d ne[d] * pts2[d][o][k] ----
    #pragma unroll
    for (int c = 0; c < 4; ++c) {
        int idx = c * 256 + t;
        int o = idx >> 3, k0 = (idx & 7) * 8;
        float a8[8] = {};
        #pragma unroll
        for (int d = 0; d < EMB; ++d) {
            bf16x8 pv = *(const bf16x8*)(pts2 + (size_t)d * 8192 + o * 64 + k0);
            #pragma unroll
            for (int e = 0; e < 8; ++e) a8[e] += ne[d] * bf2f(pv[e]);
        }
        bf16x8 w;
        #pragma unroll
        for (int e = 0; e < 8; ++e) w[e] = f2bf(a8[e]);
        *(bf16x8*)(sW + o * 72 + k0) = w;
    }
    // ---- stage eb chunk 0 ----
    #pragma unroll
    for (int c = 0; c < 4; ++c) {
        int idx = c * 256 + t;
        int r = idx >> 4, kq = (idx & 15) * 4;
        short4v s;
        s.x = f2bf(ev[c].x); s.y = f2bf(ev[c].y);
        s.z = f2bf(ev[c].z); s.w = f2bf(ev[c].w);
        *(short4v*)(sEb[0] + r * 72 + kq) = s;
    }
    __syncthreads();

    // ---- main loop over 12 R-chunks of 64 rows ----
    for (int ch = 0; ch < 12; ++ch) {
        const int cur = ch & 1, nxt = cur ^ 1;
        // issue next chunk's global loads (latency hidden under MFMA+epilogue)
        if (ch < 11) {
            #pragma unroll
            for (int c = 0; c < 4; ++c) {
                int idx = c * 256 + t;
                int r = (ch + 1) * 64 + (idx >> 4), kq = (idx & 15) * 4;
                ev[c] = *(const float4*)(ebn + (size_t)r * (NN * DIN) + kq);
            }
        }
        // GEMM: [64r x 64k] @ [64k x 128o]
        f32x4 acc[2][4] = {};
        #pragma unroll
        for (int kc = 0; kc < 2; ++kc) {
            bf16x8 a0 = *(const bf16x8*)(sEb[cur] + (m0 + l15) * 72 + kc * 32 + quad * 8);
            bf16x8 a1 = *(const bf16x8*)(sEb[cur] + (m0 + 16 + l15) * 72 + kc * 32 + quad * 8);
            #pragma unroll
            for (int tc = 0; tc < 4; ++tc) {
                bf16x8 bfr = *(const bf16x8*)(sW + (n0 + tc * 16 + l15) * 72 + kc * 32 + quad * 8);
                acc[0][tc] = __builtin_amdgcn_mfma_f32_16x16x32_bf16(a0, bfr, acc[0][tc], 0, 0, 0);
                acc[1][tc] = __builtin_amdgcn_mfma_f32_16x16x32_bf16(a1, bfr, acc[1][tc], 0, 0, 0);
            }
        }
        // epilogue into sOut[cur]
        #pragma unroll
        for (int tr = 0; tr < 2; ++tr)
            #pragma unroll
            for (int tc = 0; tc < 4; ++tc) {
                int col = n0 + tc * 16 + l15;
                #pragma unroll
                for (int r = 0; r < 4; ++r) {
                    float v = acc[tr][tc][r] + bsr[tc];
                    v = (v >= 0.f) ? v : SLOPE * v;
                    sOut[cur][(m0 + tr * 16 + quad * 4 + r) * 136 + col] = f2bf(v);
                }
            }
        // stage next chunk into the other eb buffer (vmcnt wait lands here)
        if (ch < 11) {
            #pragma unroll
            for (int c = 0; c < 4; ++c) {
                int idx = c * 256 + t;
                int r = idx >> 4, kq = (idx & 15) * 4;
                short4v s;
                s.x = f2bf(ev[c].x); s.y = f2bf(ev[c].y);
                s.z = f2bf(ev[c].z); s.w = f2bf(ev[c].w);
                *(short4v*)(sEb[nxt] + r * 72 + kq) = s;
            }
        }
        __syncthreads();                 // sOut[cur] + sEb[nxt] visible
        // contiguous 16 KB store of this chunk; drains during next chunk
        #pragma unroll
        for (int c = 0; c < 4; ++c) {
            int idx = c * 256 + t;
            *(bf16x8*)(h2n + (size_t)ch * (64 * HID) + (size_t)idx * 8) =
                *(const bf16x8*)(sOut[cur] + (idx >> 4) * 136 + (idx & 15) * 8);
        }
    }
}

// ---------------------------------------------------------------------------
// k_temporal v2: persistent per-R (grid 768 = exactly 3 blocks/CU).
// wtem[R] generated INLINE from ptt (L2-hot 512 KB) -- 25.2 MB tensor never
// exists; btem inline from bp_tem. Loops all 8 n-chunks of 64 with h2
// register prefetch. LDS 52,224 B -> 3 blocks/CU.
// ---------------------------------------------------------------------------
__global__ __launch_bounds__(256, 3)
void k_temporal(const short* __restrict__ h2, const short* __restrict__ ptt,
                const float* __restrict__ bp_tem, const float* __restrict__ time_eb,
                const float* __restrict__ W3, const float* __restrict__ b3,
                float* __restrict__ out)
{
    const int R = blockIdx.x;
    const int t = threadIdx.x;
    const int wave = t >> 6, lane = t & 63, quad = lane >> 4, l15 = lane & 15;
    const int m0 = wave * 16;

    __shared__ short sWt[128 * 136];     // 34,816 B
    __shared__ short sH2[64 * 136];      // 17,408 B

    const short* hb = h2 + (size_t)R * HID;           // + n*BT*HID walks n

    // ---- issue chunk-0 h2 loads first (L3 latency hides under wtem gen) ----
    bf16x8 hreg[4];
    #pragma unroll
    for (int c = 0; c < 4; ++c) {
        int idx = c * 256 + t;
        hreg[c] = *(const bf16x8*)(hb + (size_t)(idx >> 4) * (BT * HID) + (idx & 15) * 8);
    }
    // ---- time embedding (uniform across block) ----
    float te[EMB];
    #pragma unroll
    for (int d = 0; d < EMB; ++d) te[d] = time_eb[R * EMB + d];
    // ---- inline wtem: sWt[o][i] = sum_d te[d] * ptt[d][o][i] ----
    #pragma unroll
    for (int c = 0; c < 8; ++c) {
        int idx = c * 256 + t;
        int o = idx >> 4, i0 = (idx & 15) * 8;
        float a8[8] = {};
        #pragma unroll
        for (int d = 0; d < EMB; ++d) {
            bf16x8 pv = *(const bf16x8*)(ptt + (size_t)d * 16384 + o * 128 + i0);
            #pragma unroll
            for (int e = 0; e < 8; ++e) a8[e] += te[d] * bf2f(pv[e]);
        }
        bf16x8 w;
        #pragma unroll
        for (int e = 0; e < 8; ++e) w[e] = f2bf(a8[e]);
        *(bf16x8*)(sWt + o * 136 + i0) = w;
    }
    // ---- inline btem + W3 registers ----
    float btr[8], w3r0[8], w3r1[8];
    #pragma unroll
    for (int tc = 0; tc < 8; ++tc) {
        int o = tc * 16 + l15;
        float a = 0.f;
        #pragma unroll
        for (int d = 0; d < EMB; ++d) a += te[d] * bp_tem[d * HID + o];
        btr[tc] = a;
        w3r0[tc] = W3[2 * o]; w3r1[tc] = W3[2 * o + 1];
    }
    const float b30 = b3[0], b31 = b3[1];

    // ---- stage chunk 0 ----
    #pragma unroll
    for (int c = 0; c < 4; ++c) {
        int idx = c * 256 + t;
        *(bf16x8*)(sH2 + (idx >> 4) * 136 + (idx & 15) * 8) = hreg[c];
    }
    __syncthreads();

    // ---- loop over 8 n-chunks of 64 ----
    for (int nt = 0; nt < 8; ++nt) {
        if (nt < 7) {
            #pragma unroll
            for (int c = 0; c < 4; ++c) {
                int idx = c * 256 + t;
                hreg[c] = *(const bf16x8*)(hb + (size_t)((nt + 1) * 64 + (idx >> 4)) * (BT * HID) + (idx & 15) * 8);
            }
        }
        f32x4 acc[8] = {};
        #pragma unroll
        for (int kc = 0; kc < 4; ++kc) {
            bf16x8 a = *(const bf16x8*)(sH2 + (m0 + l15) * 136 + kc * 32 + quad * 8);
            #pragma unroll
            for (int tc = 0; tc < 8; ++tc) {
                bf16x8 b = *(const bf16x8*)(sWt + (tc * 16 + l15) * 136 + kc * 32 + quad * 8);
                acc[tc] = __builtin_amdgcn_mfma_f32_16x16x32_bf16(a, b, acc[tc], 0, 0, 0);
            }
        }
        float pl[4][2] = {};
        #pragma unroll
        for (int tc = 0; tc < 8; ++tc) {
            #pragma unroll
            for (int r = 0; r < 4; ++r) {
                float v = acc[tc][r] + btr[tc];
                v = (v >= 0.f) ? v : SLOPE * v;
                pl[r][0] += v * w3r0[tc];
                pl[r][1] += v * w3r1[tc];
            }
        }
        #pragma unroll
        for (int m = 1; m <= 8; m <<= 1)
            #pragma unroll
            for (int r = 0; r < 4; ++r) {
                pl[r][0] += __shfl_xor(pl[r][0], m);
                pl[r][1] += __shfl_xor(pl[r][1], m);
            }
        if (l15 == 0) {
            #pragma unroll
            for (int r = 0; r < 4; ++r) {
                int nrow = nt * 64 + m0 + quad * 4 + r;
                *(float2*)(out + ((size_t)R * NN + nrow) * 2) =
                    make_float2(pl[r][0] + b30, pl[r][1] + b31);
            }
        }
        __syncthreads();                 // sH2 reads done
        if (nt < 7) {
            #pragma unroll
            for (int c = 0; c < 4; ++c) {
                int idx = c * 256 + t;
                *(bf16x8*)(sH2 + (idx >> 4) * 136 + (idx & 15) * 8) = hreg[c];
            }
            __syncthreads();
        }
    }
}

extern "C" void kernel_launch(void* const* d_in, const int* in_sizes, int n_in,
                              void* d_out, int out_size, void* d_ws, size_t ws_size,
                              hipStream_t stream) {
    const float* eb        = (const float*)d_in[0];
    const float* time_eb   = (const float*)d_in[1];
    const float* node_eb   = (const float*)d_in[2];
    const float* W1        = (const float*)d_in[3];
    const float* b1        = (const float*)d_in[4];
    const float* W3        = (const float*)d_in[5];
    const float* b3        = (const float*)d_in[6];
    const float* pool_spa  = (const float*)d_in[7];
    const float* bpool_spa = (const float*)d_in[8];
    const float* pool_tem  = (const float*)d_in[9];
    const float* bpool_tem = (const float*)d_in[10];
    float* out = (float*)d_out;

    char* ws = (char*)d_ws;
    short* ptt  = (short*)(ws + OFF_PTT);
    short* pts2 = (short*)(ws + OFF_PTS2);
    float* qb   = (float*)(ws + OFF_QB);
    short* h2   = (short*)(ws + OFF_H2);

    k_prep<<<82, 256, 0, stream>>>(pool_spa, pool_tem, W1, b1, bpool_spa,
                                   ptt, pts2, qb);
    k_spatial<<<dim3(NN), 256, 0, stream>>>(eb, pts2, qb, node_eb, h2);
    k_temporal<<<dim3(BT), 256, 0, stream>>>(h2, ptt, bpool_tem, time_eb, W3, b3, out);
}